// Round 1
// baseline (121.071 us; speedup 1.0000x reference)
//
#include <hip/hip_runtime.h>

// CatmullRomActivation — MI355X (gfx950)
//
// Reference quirk: coef is sample-major flat, Q is neuron-major flat, multiplied
// on the same linear index q. So for out.flat[q]:
//   u-part   : x.flat[q]                     (linear, coalesced)
//   p0/points: x[iq][jq], jq=q/M, iq=q%M     (transposed traversal, cp row jq)
//
// Strategy: 64x64 tile in (iq, jq) space per 256-thread block.
//   - stage x[iq0:+64][jq0:+64] in LDS via coalesced float4 (transpose tile)
//   - stage 64 neurons x 10 control points in LDS
//   - each thread: float4 linear x load, 4 transposed LDS reads, float4 store

constexpr int M_DIM = 8192;   // samples
constexpr int N_DIM = 2048;   // neurons
constexpr int KPTS  = 10;     // control points per neuron
constexpr int TILE  = 64;
constexpr int PITCH = TILE + 1;  // 65: transposed reads land 2-way max (free)

__global__ __launch_bounds__(256)
void catmull_rom_kernel(const float* __restrict__ x,
                        const float* __restrict__ cp,
                        float* __restrict__ out)
{
    __shared__ float xt[TILE * PITCH];     // xt[r*PITCH+c] = x[iq0+r][jq0+c]
    __shared__ float cps[TILE * KPTS];     // cps[c*KPTS+k] = cp[jq0+c][k]

    const int t   = threadIdx.x;
    const int iq0 = blockIdx.x * TILE;
    const int jq0 = blockIdx.y * TILE;

    // ---- Phase 1a: stage x tile (coalesced along neuron dim) ----
    #pragma unroll
    for (int k = 0; k < 4; ++k) {
        int f  = t + k * 256;          // 0..1023 float4 units
        int r  = f >> 4;               // iq_local 0..63
        int c4 = (f & 15) << 2;        // jq_local base
        float4 v = *reinterpret_cast<const float4*>(
            x + (size_t)(iq0 + r) * N_DIM + (jq0 + c4));
        float* dst = &xt[r * PITCH + c4];
        dst[0] = v.x; dst[1] = v.y; dst[2] = v.z; dst[3] = v.w;
    }
    // ---- Phase 1b: stage control points (640 contiguous floats) ----
    for (int idx = t; idx < TILE * KPTS; idx += 256) {
        cps[idx] = cp[jq0 * KPTS + idx];
    }
    __syncthreads();

    // ---- Phase 2: 4096 outputs / block, 16 per thread as 4x float4 ----
    #pragma unroll
    for (int k = 0; k < 4; ++k) {
        int f  = t + k * 256;
        int tj = f >> 4;               // neuron-in-tile 0..63
        int g  = (f & 15) << 2;        // iq_local base (4 consecutive)
        size_t q = (size_t)(jq0 + tj) * M_DIM + (size_t)(iq0 + g);

        float4 xl = *reinterpret_cast<const float4*>(x + q);  // x.flat[q]
        const float* cpn = &cps[tj * KPTS];
        float xle[4] = {xl.x, xl.y, xl.z, xl.w};
        float res[4];
        #pragma unroll
        for (int e = 0; e < 4; ++e) {
            // transposed x value -> segment index p0 (match ref arithmetic)
            float xq  = xt[(g + e) * PITCH + tj];
            float p0f = floorf((xq + 2.0f) * 6.0f / 4.0f + 1.0f);
            int   p0  = (int)p0f;
            p0 = (xq <= -2.0f) ? 1 : p0;
            p0 = (xq >=  2.0f) ? 7 : p0;

            float Pm1 = cpn[p0 - 1];
            float P0  = cpn[p0];
            float P1  = cpn[p0 + 1];
            float P2  = cpn[p0 + 2];

            // local parameter from the LINEAR x value
            float xv = xle[e];
            float tt = 2.0f * xv;           // x / 0.5
            float u  = tt - floorf(tt);
            float u2 = u * u;
            float u3 = u2 * u;
            // (U @ B) columns, already in reversed pairing with P[-1..2]
            float c0 = -0.5f*u3 +       u2 - 0.5f*u;         // pairs P2
            float c1 =  1.5f*u3 - 2.5f*u2 + 1.0f;            // pairs P1
            float c2 = -1.5f*u3 + 2.0f*u2 + 0.5f*u;          // pairs P0
            float c3 =  0.5f*u3 - 0.5f*u2;                   // pairs Pm1
            res[e] = c3*Pm1 + c2*P0 + c1*P1 + c0*P2;
        }
        float4 ov = {res[0], res[1], res[2], res[3]};
        *reinterpret_cast<float4*>(out + q) = ov;
    }
}

extern "C" void kernel_launch(void* const* d_in, const int* in_sizes, int n_in,
                              void* d_out, int out_size, void* d_ws, size_t ws_size,
                              hipStream_t stream) {
    const float* x  = (const float*)d_in[0];   // (M, N) f32
    const float* cp = (const float*)d_in[1];   // (N, K) f32
    float* out = (float*)d_out;                // (M, N) f32

    dim3 grid(M_DIM / TILE, N_DIM / TILE);     // (128, 32)
    dim3 block(256);
    catmull_rom_kernel<<<grid, block, 0, stream>>>(x, cp, out);
}

// Round 3
// 117.809 us; speedup vs baseline: 1.0277x; 1.0277x over previous
//
#include <hip/hip_runtime.h>

// CatmullRomActivation — MI355X (gfx950), round 3: R2 ILP restructure with
// compile fix (nontemporal store needs a native clang vector type, not HIP's
// float4 class).
//
// Reference quirk: coef is sample-major flat, Q is neuron-major flat, multiplied
// on the same linear index q. So for out.flat[q]:
//   u-part   : x.flat[q]                     (linear, coalesced)
//   p0/points: x[iq][jq], jq=q/M, iq=q%M     (transposed traversal, cp row jq)
//
// R1 showed latency-bound (VALU 26%, HBM 51%, VGPR=20 -> no ILP). This round:
//  - issue ALL global loads (tile + cp + linear) before the barrier; the
//    linear loads are LDS-independent so their latency hides behind staging
//  - batch the 16 transposed LDS reads into registers before compute
//  - non-temporal stores: keep x resident in L3 so its 2nd read stays a hit
//    (R1 FETCH=65 MB proved L3 absorbs the re-read; protect that)

constexpr int M_DIM = 8192;   // samples
constexpr int N_DIM = 2048;   // neurons
constexpr int KPTS  = 10;     // control points per neuron
constexpr int TILE  = 64;
constexpr int PITCH = TILE + 1;  // 65: transposed reads max 2-way (free, m136)

typedef float floatx4 __attribute__((ext_vector_type(4)));  // native vec for NT store

__global__ __launch_bounds__(256)
void catmull_rom_kernel(const float* __restrict__ x,
                        const float* __restrict__ cp,
                        float* __restrict__ out)
{
    __shared__ float xt[TILE * PITCH];     // xt[r*PITCH+c] = x[iq0+r][jq0+c]
    __shared__ float cps[TILE * KPTS];     // cps[c*KPTS+k] = cp[jq0+c][k]

    const int t   = threadIdx.x;
    const int iq0 = blockIdx.x * TILE;
    const int jq0 = blockIdx.y * TILE;

    // ---- issue tile loads first (barrier-critical) ----
    float4 tv[4];
    #pragma unroll
    for (int k = 0; k < 4; ++k) {
        int f = t + k * 256;
        int r = f >> 4, c4 = (f & 15) << 2;
        tv[k] = *reinterpret_cast<const float4*>(
            x + (size_t)(iq0 + r) * N_DIM + (jq0 + c4));
    }
    // ---- cp loads (640 floats over 256 threads) ----
    const float* cpb = cp + (size_t)jq0 * KPTS;
    float cv0 = cpb[t];
    float cv1 = cpb[t + 256];
    float cv2 = (t < TILE * KPTS - 512) ? cpb[t + 512] : 0.0f;

    // ---- issue linear loads NOW: independent of LDS, latency hides behind
    //      the staging writes + barrier drain ----
    float4 xl[4];
    size_t q[4];
    #pragma unroll
    for (int k = 0; k < 4; ++k) {
        int f  = t + k * 256;
        int tj = f >> 4, g = (f & 15) << 2;
        q[k]  = (size_t)(jq0 + tj) * M_DIM + (size_t)(iq0 + g);
        xl[k] = *reinterpret_cast<const float4*>(x + q[k]);
    }

    // ---- stage tile + cp to LDS ----
    #pragma unroll
    for (int k = 0; k < 4; ++k) {
        int f = t + k * 256;
        int r = f >> 4, c4 = (f & 15) << 2;
        float* dst = &xt[r * PITCH + c4];
        dst[0] = tv[k].x; dst[1] = tv[k].y; dst[2] = tv[k].z; dst[3] = tv[k].w;
    }
    cps[t]       = cv0;
    cps[t + 256] = cv1;
    if (t < TILE * KPTS - 512) cps[t + 512] = cv2;
    __syncthreads();

    // ---- batched transposed LDS reads (16 independent ds_read_b32) ----
    float xq[16];
    #pragma unroll
    for (int k = 0; k < 4; ++k) {
        int f = t + k * 256;
        int tj = f >> 4, g = (f & 15) << 2;
        #pragma unroll
        for (int e = 0; e < 4; ++e)
            xq[k * 4 + e] = xt[(g + e) * PITCH + tj];
    }

    // ---- compute + store ----
    #pragma unroll
    for (int k = 0; k < 4; ++k) {
        int f  = t + k * 256;
        int tj = f >> 4;
        const float* cpn = &cps[tj * KPTS];
        float xle[4] = {xl[k].x, xl[k].y, xl[k].z, xl[k].w};
        float res[4];
        #pragma unroll
        for (int e = 0; e < 4; ++e) {
            float xv_t = xq[k * 4 + e];
            float p0f  = floorf((xv_t + 2.0f) * 1.5f + 1.0f);   // == *6/4
            int   p0   = (int)p0f;
            p0 = (xv_t <= -2.0f) ? 1 : p0;
            p0 = (xv_t >=  2.0f) ? 7 : p0;

            float Pm1 = cpn[p0 - 1];
            float P0  = cpn[p0];
            float P1  = cpn[p0 + 1];
            float P2  = cpn[p0 + 2];

            float xv = xle[e];
            float tt = 2.0f * xv;            // x / 0.5
            float u  = tt - floorf(tt);
            float u2 = u * u;
            float u3 = u2 * u;
            float c0 = -0.5f*u3 +       u2 - 0.5f*u;   // pairs P2
            float c1 =  1.5f*u3 - 2.5f*u2 + 1.0f;      // pairs P1
            float c2 = -1.5f*u3 + 2.0f*u2 + 0.5f*u;    // pairs P0
            float c3 =  0.5f*u3 - 0.5f*u2;             // pairs Pm1
            res[e] = c3*Pm1 + c2*P0 + c1*P1 + c0*P2;
        }
        floatx4 ov = {res[0], res[1], res[2], res[3]};
        __builtin_nontemporal_store(ov, reinterpret_cast<floatx4*>(out + q[k]));
    }
}

extern "C" void kernel_launch(void* const* d_in, const int* in_sizes, int n_in,
                              void* d_out, int out_size, void* d_ws, size_t ws_size,
                              hipStream_t stream) {
    const float* x  = (const float*)d_in[0];   // (M, N) f32
    const float* cp = (const float*)d_in[1];   // (N, K) f32
    float* out = (float*)d_out;                // (M, N) f32

    dim3 grid(M_DIM / TILE, N_DIM / TILE);     // (128, 32)
    dim3 block(256);
    catmull_rom_kernel<<<grid, block, 0, stream>>>(x, cp, out);
}